// Round 10
// baseline (370.131 us; speedup 1.0000x reference)
//
#include <hip/hip_runtime.h>
#include <math.h>

#define HID   1024
#define STT   4096
#define MTOK  4096   // B*L
#define LSEQ  2048
#define NCHUNK 32
#define CHUNK  64
#define VOCAB  62

typedef __attribute__((ext_vector_type(8))) short short8v;
typedef __attribute__((ext_vector_type(4))) float float4v;

typedef const __attribute__((address_space(1))) void* gptr_t;
typedef __attribute__((address_space(3))) void* lptr_t;

__device__ __forceinline__ float sigmoidf_(float x) {
    return 1.0f / (1.0f + __expf(-x));
}
__device__ __forceinline__ unsigned short f2bf(float f) {
    unsigned int u = __float_as_uint(f);
    unsigned int r = (u + 0x7fffu + ((u >> 16) & 1u)) >> 16;
    return (unsigned short)r;
}
__device__ __forceinline__ float bf2f(unsigned short b) {
    return __uint_as_float(((unsigned int)b) << 16);
}

// ---------------- cast + transpose: src[R][C] f32 -> dst[C][R] bf16 ----------
__global__ __launch_bounds__(256) void cast_transpose_kernel(
    const float* __restrict__ src, unsigned short* __restrict__ dst, int R, int C)
{
    __shared__ float tile[32][33];
    int c0 = blockIdx.x * 32, r0 = blockIdx.y * 32;
    int t = threadIdx.x;
    int r = t >> 3, c4 = (t & 7) << 2;
    float4 v = *(const float4*)(src + (size_t)(r0 + r) * C + c0 + c4);
    tile[r][c4 + 0] = v.x; tile[r][c4 + 1] = v.y;
    tile[r][c4 + 2] = v.z; tile[r][c4 + 3] = v.w;
    __syncthreads();
    int oc = t >> 3;
    int orr = (t & 7) << 2;
    ushort4 o;
    o.x = f2bf(tile[orr + 0][oc]); o.y = f2bf(tile[orr + 1][oc]);
    o.z = f2bf(tile[orr + 2][oc]); o.w = f2bf(tile[orr + 3][oc]);
    *(ushort4*)(dst + (size_t)(c0 + oc) * R + r0 + orr) = o;
}

// ---------------- embedding gather + RMSNorm -> bf16 ----------------
__global__ __launch_bounds__(256) void embed_norm_kernel(
    const int* __restrict__ tokens, const float* __restrict__ embed_w,
    const float* __restrict__ norm_w, unsigned short* __restrict__ xn)
{
    int m = blockIdx.x;
    int t = threadIdx.x;
    int tok = tokens[m];
    float4 x = ((const float4*)(embed_w + (size_t)tok * HID))[t];
    float ss = x.x * x.x + x.y * x.y + x.z * x.z + x.w * x.w;
    for (int off = 32; off > 0; off >>= 1) ss += __shfl_down(ss, off);
    __shared__ float wsum[4];
    if ((t & 63) == 0) wsum[t >> 6] = ss;
    __syncthreads();
    float tot = wsum[0] + wsum[1] + wsum[2] + wsum[3];
    float scale = rsqrtf(tot / (float)HID + 1e-6f);
    float4 w4 = ((const float4*)norm_w)[t];
    ushort4 o;
    o.x = f2bf(x.x * scale * w4.x); o.y = f2bf(x.y * scale * w4.y);
    o.z = f2bf(x.z * scale * w4.z); o.w = f2bf(x.w * scale * w4.w);
    *(ushort4*)(xn + (size_t)m * HID + (t << 2)) = o;
}

// ---------------- MFMA GEMM 1: proj = xn @ in_w + in_b  (bf16 out) ----------
// Round-9 state (frozen): 256x256, BK=64, 8 waves, 2 LDS bufs, 4-phase
// counted-vmcnt template, conflict-free chunk swizzle, XCD cell swizzle.
__global__ __launch_bounds__(512, 2) void gemm_in_mfma(
    const unsigned short* __restrict__ A, const unsigned short* __restrict__ B,
    const float* __restrict__ bias, unsigned short* __restrict__ Cout)
{
    extern __shared__ unsigned short lds[];   // 2 bufs * 32768 shorts = 128 KiB
    int tid = threadIdx.x;
    int wid = tid >> 6, lane = tid & 63;
    int wg = blockIdx.x;
    int xcd = wg & 7, loc = wg >> 3;
    int by = ((xcd >> 1) << 2) + (loc & 3);   // 0..15
    int bx = ((xcd & 1) << 5) + (loc >> 2);   // 0..63
    int m0 = by * 256, n0 = bx * 256;
    int wm = wid >> 2, wn = wid & 3;
    int lr = lane & 15, lk = lane >> 4;

    int cb0 = wid * 64, cb1 = 512 + wid * 64;
    int p0 = cb0 + lane, p1 = cb1 + lane;
    int row0 = p0 >> 2, ks0 = (p0 & 3) ^ ((row0 >> 1) & 3);
    int row1 = p1 >> 2, ks1 = (p1 & 3) ^ ((row1 >> 1) & 3);

#define SHALF(SRC, base0, b, which, kt, kk) do {                                 \
    unsigned short* _d = lds + (b) * 32768 + (which) * 16384 + (kk) * 8192;      \
    __builtin_amdgcn_global_load_lds(                                            \
        (gptr_t)(const void*)((SRC) + (size_t)((base0) + row0) * 1024 +          \
                              (kt) * 64 + (kk) * 32 + ks0 * 8),                  \
        (lptr_t)(void*)(_d + (size_t)cb0 * 8), 16, 0, 0);                        \
    __builtin_amdgcn_global_load_lds(                                            \
        (gptr_t)(const void*)((SRC) + (size_t)((base0) + row1) * 1024 +          \
                              (kt) * 64 + (kk) * 32 + ks1 * 8),                  \
        (lptr_t)(void*)(_d + (size_t)cb1 * 8), 16, 0, 0);                        \
} while (0)

    int ksw = lk ^ ((lr >> 1) & 3);

#define RD_A(b, kk, mf) \
    (*(const short8v*)&lds[(b) * 32768 + (kk) * 8192 + \
        (((wm * 128 + (mf) * 16 + lr) << 2) + ksw) * 8])
#define RD_B(b, kk, nf) \
    (*(const short8v*)&lds[(b) * 32768 + 16384 + (kk) * 8192 + \
        (((wn * 64 + (nf) * 16 + lr) << 2) + ksw) * 8])

#define MFMA8x2(AF, B0, B1, n0i, n1i) do {                                       \
    __builtin_amdgcn_s_setprio(1);                                               \
    _Pragma("unroll")                                                            \
    for (int mf = 0; mf < 8; mf++) {                                             \
        acc[mf][n0i] = __builtin_amdgcn_mfma_f32_16x16x32_bf16(                  \
            (AF)[mf], (B0), acc[mf][n0i], 0, 0, 0);                              \
        acc[mf][n1i] = __builtin_amdgcn_mfma_f32_16x16x32_bf16(                  \
            (AF)[mf], (B1), acc[mf][n1i], 0, 0, 0);                              \
    }                                                                            \
    __builtin_amdgcn_s_setprio(0);                                               \
} while (0)

#define BAR_IN()  do { __builtin_amdgcn_s_barrier();                              \
    asm volatile("s_waitcnt lgkmcnt(0)" ::: "memory");                           \
    __builtin_amdgcn_sched_barrier(0); } while (0)
#define BAR_OUT() do { asm volatile("" ::: "memory");                             \
    __builtin_amdgcn_s_barrier(); } while (0)

    float4v acc[8][4];
    float4v z = {0.f, 0.f, 0.f, 0.f};
    #pragma unroll
    for (int i = 0; i < 8; i++)
        #pragma unroll
        for (int j = 0; j < 4; j++) acc[i][j] = z;

    SHALF(A, m0, 0, 0, 0, 0); SHALF(B, n0, 0, 1, 0, 0);
    SHALF(A, m0, 0, 0, 0, 1); SHALF(B, n0, 0, 1, 0, 1);
    asm volatile("s_waitcnt vmcnt(0)" ::: "memory");
    __builtin_amdgcn_s_barrier();

    short8v af[8], bf0, bf1;

    for (int kt = 0; kt < 16; ++kt) {
        int cur = kt & 1, nxt = cur ^ 1;
        int ktn = kt < 15 ? kt + 1 : 15;
        // phase 0: kk0, nf0-1
        #pragma unroll
        for (int mf = 0; mf < 8; mf++) af[mf] = RD_A(cur, 0, mf);
        bf0 = RD_B(cur, 0, 0); bf1 = RD_B(cur, 0, 1);
        asm volatile("s_waitcnt vmcnt(4)" ::: "memory");
        SHALF(A, m0, nxt, 0, ktn, 0);
        BAR_IN();
        MFMA8x2(af, bf0, bf1, 0, 1);
        BAR_OUT();
        // phase 1: kk0, nf2-3
        bf0 = RD_B(cur, 0, 2); bf1 = RD_B(cur, 0, 3);
        SHALF(B, n0, nxt, 1, ktn, 0);
        BAR_IN();
        MFMA8x2(af, bf0, bf1, 2, 3);
        BAR_OUT();
        // phase 2: kk1, nf0-1
        #pragma unroll
        for (int mf = 0; mf < 8; mf++) af[mf] = RD_A(cur, 1, mf);
        bf0 = RD_B(cur, 1, 0); bf1 = RD_B(cur, 1, 1);
        asm volatile("s_waitcnt vmcnt(4)" ::: "memory");
        SHALF(A, m0, nxt, 0, ktn, 1);
        BAR_IN();
        MFMA8x2(af, bf0, bf1, 0, 1);
        BAR_OUT();
        // phase 3: kk1, nf2-3
        bf0 = RD_B(cur, 1, 2); bf1 = RD_B(cur, 1, 3);
        SHALF(B, n0, nxt, 1, ktn, 1);
        BAR_IN();
        MFMA8x2(af, bf0, bf1, 2, 3);
        BAR_OUT();
    }

    int rbase = lk << 2;
    #pragma unroll
    for (int mf = 0; mf < 8; mf++)
        #pragma unroll
        for (int nf = 0; nf < 4; nf++) {
            int n = n0 + wn * 64 + nf * 16 + lr;
            float bv = bias[n];
            #pragma unroll
            for (int q = 0; q < 4; q++) {
                int m = m0 + wm * 128 + mf * 16 + rbase + q;
                Cout[(size_t)m * 16384 + n] = f2bf(acc[mf][nf][q] + bv);
            }
        }
#undef SHALF
#undef RD_A
#undef RD_B
#undef MFMA8x2
#undef BAR_IN
#undef BAR_OUT
}

// ---------------- MFMA GEMM 2: out = y @ out_w + out_b + residual (f32 out) --
// 128x128 tile, BK=32, 4 waves (2x2), 3-buffer depth-2 pipeline, chunk swizzle.
__global__ __launch_bounds__(256, 3) void gemm_out_mfma(
    const unsigned short* __restrict__ A, const unsigned short* __restrict__ B,
    const float* __restrict__ out_b, const int* __restrict__ tokens,
    const float* __restrict__ embed_w, float* __restrict__ Cout)
{
    extern __shared__ unsigned short lds[];   // 3 bufs * (4096 A + 4096 B) = 48 KiB
    int tid = threadIdx.x;
    int wid = tid >> 6, lane = tid & 63;
    int wg = blockIdx.x;                      // 256 WGs: 8 n-tiles x 32 m-tiles
    int swz = (wg & 7) * 32 + (wg >> 3);
    int bx = swz & 7;
    int by = swz >> 3;
    int m0 = by * 128, n0 = bx * 128;
    int wm = wid >> 1, wn = wid & 1;
    int lr = lane & 15, lk = lane >> 4;

    auto stage = [&](int b, int kt) {
        unsigned short* As = lds + b * 8192;
        unsigned short* Bs = As + 4096;
        #pragma unroll
        for (int i = 0; i < 2; i++) {
            int cb = i * 256 + wid * 64;
            int p = cb + lane;
            int row = p >> 2;
            int ks = (p & 3) ^ ((row >> 1) & 3);
            __builtin_amdgcn_global_load_lds(
                (gptr_t)(const void*)(A + (size_t)(m0 + row) * 4096 + kt + ks * 8),
                (lptr_t)(void*)(As + (size_t)cb * 8), 16, 0, 0);
            __builtin_amdgcn_global_load_lds(
                (gptr_t)(const void*)(B + (size_t)(n0 + row) * 4096 + kt + ks * 8),
                (lptr_t)(void*)(Bs + (size_t)cb * 8), 16, 0, 0);
        }
    };

    float4v acc[4][4];
    float4v z = {0.f, 0.f, 0.f, 0.f};
    #pragma unroll
    for (int i = 0; i < 4; i++)
        #pragma unroll
        for (int j = 0; j < 4; j++) acc[i][j] = z;

    const int nt = 4096 / 32;
    stage(0, 0); stage(1, 32);

    int ksw = lk ^ ((lr >> 1) & 3);
    int aoff = lr * 4 + ksw;

    for (int t = 0; t < nt; ++t) {
        if (t + 2 < nt) stage((t + 2) % 3, (t + 2) * 32);
        if (t + 2 < nt)      asm volatile("s_waitcnt vmcnt(8)" ::: "memory");
        else if (t + 1 < nt) asm volatile("s_waitcnt vmcnt(4)" ::: "memory");
        else                 asm volatile("s_waitcnt vmcnt(0)" ::: "memory");
        __builtin_amdgcn_s_barrier();
        asm volatile("" ::: "memory");
        const unsigned short* As = lds + (t % 3) * 8192;
        const unsigned short* Bs = As + 4096;
        short8v af[4], bfr[4];
        #pragma unroll
        for (int f = 0; f < 4; f++) {
            af[f]  = *(const short8v*)&As[((wm * 64 + f * 16) * 4 + aoff) * 8];
            bfr[f] = *(const short8v*)&Bs[((wn * 64 + f * 16) * 4 + aoff) * 8];
        }
        __builtin_amdgcn_s_setprio(1);
        #pragma unroll
        for (int mf = 0; mf < 4; mf++)
            #pragma unroll
            for (int nf = 0; nf < 4; nf++)
                acc[mf][nf] = __builtin_amdgcn_mfma_f32_16x16x32_bf16(
                    af[mf], bfr[nf], acc[mf][nf], 0, 0, 0);
        __builtin_amdgcn_s_setprio(0);
        asm volatile("" ::: "memory");
        __builtin_amdgcn_s_barrier();
    }

    int rbase = lk << 2;
    #pragma unroll
    for (int mf = 0; mf < 4; mf++) {
        #pragma unroll
        for (int q = 0; q < 4; q++) {
            int m = m0 + wm * 64 + mf * 16 + rbase + q;
            int tok = tokens[m];
            #pragma unroll
            for (int nf = 0; nf < 4; nf++) {
                int n = n0 + wn * 64 + nf * 16 + lr;
                float v = acc[mf][nf][q] + out_b[n] + embed_w[(size_t)tok * HID + n];
                Cout[(size_t)m * HID + n] = v;
            }
        }
    }
}

// ---------------- scan phase 1: per-chunk (A, H), 4 channels/thread ----------
// grid 256 = 4 sg x 32 q x 2 b; ushort4 (8B) vectorized gate loads
__global__ __launch_bounds__(256) void scan_phase1(
    const unsigned short* __restrict__ proj,
    float* __restrict__ chunkA, float* __restrict__ chunkH)
{
    int bid = blockIdx.x;
    int sg = bid & 3, q = (bid >> 2) & 31, b = bid >> 7;
    int s0 = sg * 1024 + threadIdx.x * 4;
    const unsigned short* p = proj + (size_t)(b * LSEQ + q * CHUNK) * 16384 + s0;
    float Aa[4] = {1.f, 1.f, 1.f, 1.f}, Hh[4] = {0.f, 0.f, 0.f, 0.f};
    for (int t = 0; t < CHUNK; t++) {
        ushort4 X = *(const ushort4*)(p);
        ushort4 Al = *(const ushort4*)(p + 4096);
        ushort4 Bl = *(const ushort4*)(p + 8192);
        const unsigned short* xp = (const unsigned short*)&X;
        const unsigned short* ap = (const unsigned short*)&Al;
        const unsigned short* bp = (const unsigned short*)&Bl;
        #pragma unroll
        for (int j = 0; j < 4; j++) {
            float a = sigmoidf_(bf2f(ap[j]));
            float bx = sigmoidf_(bf2f(bp[j])) * bf2f(xp[j]);
            Hh[j] = fmaf(a, Hh[j], bx);
            Aa[j] *= a;
        }
        p += 16384;
    }
    #pragma unroll
    for (int j = 0; j < 4; j++) {
        int ch = b * STT + s0 + j;
        chunkA[ch * NCHUNK + q] = Aa[j];
        chunkH[ch * NCHUNK + q] = Hh[j];
    }
}

__global__ __launch_bounds__(256) void scan_phase2(
    const float* __restrict__ chunkA, const float* __restrict__ chunkH,
    float* __restrict__ carry)
{
    int ch = blockIdx.x * 256 + threadIdx.x;
    float c = 0.f;
    for (int q = 0; q < NCHUNK; q++) {
        carry[ch * NCHUNK + q] = c;
        c = fmaf(chunkA[ch * NCHUNK + q], c, chunkH[ch * NCHUNK + q]);
    }
}

// ---------------- scan phase 3: y = sig(c_l)*h, 4 channels/thread ----------
__global__ __launch_bounds__(256) void scan_phase3(
    const unsigned short* __restrict__ proj, const float* __restrict__ carry,
    unsigned short* __restrict__ y)
{
    int bid = blockIdx.x;
    int sg = bid & 3, q = (bid >> 2) & 31, b = bid >> 7;
    int s0 = sg * 1024 + threadIdx.x * 4;
    float h[4];
    #pragma unroll
    for (int j = 0; j < 4; j++)
        h[j] = carry[(b * STT + s0 + j) * NCHUNK + q];
    const unsigned short* p = proj + (size_t)(b * LSEQ + q * CHUNK) * 16384 + s0;
    unsigned short* yp = y + (size_t)(b * LSEQ + q * CHUNK) * STT + s0;
    for (int t = 0; t < CHUNK; t++) {
        ushort4 X = *(const ushort4*)(p);
        ushort4 Al = *(const ushort4*)(p + 4096);
        ushort4 Bl = *(const ushort4*)(p + 8192);
        ushort4 Cl = *(const ushort4*)(p + 12288);
        const unsigned short* xp = (const unsigned short*)&X;
        const unsigned short* ap = (const unsigned short*)&Al;
        const unsigned short* bp = (const unsigned short*)&Bl;
        const unsigned short* cp = (const unsigned short*)&Cl;
        ushort4 o;
        unsigned short* op = (unsigned short*)&o;
        #pragma unroll
        for (int j = 0; j < 4; j++) {
            float a = sigmoidf_(bf2f(ap[j]));
            float bx = sigmoidf_(bf2f(bp[j])) * bf2f(xp[j]);
            h[j] = fmaf(a, h[j], bx);
            op[j] = f2bf(sigmoidf_(bf2f(cp[j])) * h[j]);
        }
        *(ushort4*)yp = o;
        p += 16384; yp += STT;
    }
}

// ---------------- head GEMM: 256 threads/token, 4-way k-split ----------------
__global__ __launch_bounds__(256) void head_kernel(
    const float* __restrict__ out, const float* __restrict__ head_w,
    const float* __restrict__ head_b, float* __restrict__ logits)
{
    __shared__ float row[HID];
    __shared__ float part[4][64];
    int m = blockIdx.x;
    int t = threadIdx.x;
    ((float4*)row)[t] = ((const float4*)(out + (size_t)m * HID))[t];
    __syncthreads();
    int v = t & 63, ks = t >> 6;
    float s = 0.f;
    if (v < VOCAB) {
        const float* wcol = head_w + (size_t)(ks * 256) * VOCAB + v;
        const float* rb = row + ks * 256;
        #pragma unroll 4
        for (int k = 0; k < 256; k++)
            s = fmaf(rb[k], wcol[(size_t)k * VOCAB], s);
    }
    part[ks][v] = s;
    __syncthreads();
    if (t < VOCAB)
        logits[(size_t)m * VOCAB + t] =
            part[0][t] + part[1][t] + part[2][t] + part[3][t] + head_b[t];
}

extern "C" void kernel_launch(void* const* d_in, const int* in_sizes, int n_in,
                              void* d_out, int out_size, void* d_ws, size_t ws_size,
                              hipStream_t stream) {
    const int*   tokens  = (const int*)d_in[0];
    const float* embed_w = (const float*)d_in[1];
    const float* norm_w  = (const float*)d_in[2];
    const float* in_w    = (const float*)d_in[3];
    const float* in_b    = (const float*)d_in[4];
    const float* out_w   = (const float*)d_in[5];
    const float* out_b   = (const float*)d_in[6];
    const float* head_w  = (const float*)d_in[7];
    const float* head_b  = (const float*)d_in[8];
    float* logits = (float*)d_out;

    char* w = (char*)d_ws;
    unsigned short* proj   = (unsigned short*)w;                    // 128 MiB
    unsigned short* y      = (unsigned short*)(w + 134217728);      // 32 MiB
    unsigned short* in_wT  = (unsigned short*)(w + 167772160);      // 32 MiB
    float*          outbuf = (float*)(w + 167772160);               // reuses in_wT (16 MiB)
    unsigned short* xn     = (unsigned short*)(w + 201326592);      // 8 MiB
    unsigned short* out_wT = (unsigned short*)(w + 201326592);      // reuses xn (8 MiB)
    float* chunkA = (float*)(w + 209715200);
    float* chunkH = chunkA + 8192 * NCHUNK;
    float* carry  = chunkH + 8192 * NCHUNK;

    hipLaunchKernelGGL(cast_transpose_kernel, dim3(16384 / 32, 1024 / 32), dim3(256), 0, stream,
                       in_w, in_wT, 1024, 16384);
    hipLaunchKernelGGL(embed_norm_kernel, dim3(MTOK), dim3(256), 0, stream,
                       tokens, embed_w, norm_w, xn);
    hipLaunchKernelGGL(gemm_in_mfma, dim3(1024), dim3(512), 131072, stream,
                       xn, in_wT, in_b, proj);
    hipLaunchKernelGGL(scan_phase1, dim3(256), dim3(256), 0, stream,
                       proj, chunkA, chunkH);
    hipLaunchKernelGGL(scan_phase2, dim3(32), dim3(256), 0, stream,
                       chunkA, chunkH, carry);
    hipLaunchKernelGGL(scan_phase3, dim3(256), dim3(256), 0, stream,
                       proj, carry, y);
    hipLaunchKernelGGL(cast_transpose_kernel, dim3(1024 / 32, 4096 / 32), dim3(256), 0, stream,
                       out_w, out_wT, 4096, 1024);
    hipLaunchKernelGGL(gemm_out_mfma, dim3(256), dim3(256), 49152, stream,
                       y, out_wT, out_b, tokens, embed_w, outbuf);
    hipLaunchKernelGGL(head_kernel, dim3(MTOK), dim3(256), 0, stream,
                       outbuf, head_w, head_b, logits);
}

// Round 12
// 311.957 us; speedup vs baseline: 1.1865x; 1.1865x over previous
//
#include <hip/hip_runtime.h>
#include <math.h>

#define HID   1024
#define STT   4096
#define MTOK  4096   // B*L
#define LSEQ  2048
#define NCHUNK 64
#define CHUNK  32
#define VOCAB  62

typedef __attribute__((ext_vector_type(8))) short short8v;
typedef __attribute__((ext_vector_type(4))) float float4v;

typedef const __attribute__((address_space(1))) void* gptr_t;
typedef __attribute__((address_space(3))) void* lptr_t;

__device__ __forceinline__ float sigmoidf_(float x) {
    return 1.0f / (1.0f + __expf(-x));
}
__device__ __forceinline__ unsigned short f2bf(float f) {
    unsigned int u = __float_as_uint(f);
    unsigned int r = (u + 0x7fffu + ((u >> 16) & 1u)) >> 16;
    return (unsigned short)r;
}
__device__ __forceinline__ float bf2f(unsigned short b) {
    return __uint_as_float(((unsigned int)b) << 16);
}

// ---------------- cast + transpose: src[R][C] f32 -> dst[C][R] bf16 ----------
__global__ __launch_bounds__(256) void cast_transpose_kernel(
    const float* __restrict__ src, unsigned short* __restrict__ dst, int R, int C)
{
    __shared__ float tile[32][33];
    int c0 = blockIdx.x * 32, r0 = blockIdx.y * 32;
    int t = threadIdx.x;
    int r = t >> 3, c4 = (t & 7) << 2;
    float4 v = *(const float4*)(src + (size_t)(r0 + r) * C + c0 + c4);
    tile[r][c4 + 0] = v.x; tile[r][c4 + 1] = v.y;
    tile[r][c4 + 2] = v.z; tile[r][c4 + 3] = v.w;
    __syncthreads();
    int oc = t >> 3;
    int orr = (t & 7) << 2;
    ushort4 o;
    o.x = f2bf(tile[orr + 0][oc]); o.y = f2bf(tile[orr + 1][oc]);
    o.z = f2bf(tile[orr + 2][oc]); o.w = f2bf(tile[orr + 3][oc]);
    *(ushort4*)(dst + (size_t)(c0 + oc) * R + r0 + orr) = o;
}

// ---------------- embedding gather + RMSNorm -> bf16 ----------------
__global__ __launch_bounds__(256) void embed_norm_kernel(
    const int* __restrict__ tokens, const float* __restrict__ embed_w,
    const float* __restrict__ norm_w, unsigned short* __restrict__ xn)
{
    int m = blockIdx.x;
    int t = threadIdx.x;
    int tok = tokens[m];
    float4 x = ((const float4*)(embed_w + (size_t)tok * HID))[t];
    float ss = x.x * x.x + x.y * x.y + x.z * x.z + x.w * x.w;
    for (int off = 32; off > 0; off >>= 1) ss += __shfl_down(ss, off);
    __shared__ float wsum[4];
    if ((t & 63) == 0) wsum[t >> 6] = ss;
    __syncthreads();
    float tot = wsum[0] + wsum[1] + wsum[2] + wsum[3];
    float scale = rsqrtf(tot / (float)HID + 1e-6f);
    float4 w4 = ((const float4*)norm_w)[t];
    ushort4 o;
    o.x = f2bf(x.x * scale * w4.x); o.y = f2bf(x.y * scale * w4.y);
    o.z = f2bf(x.z * scale * w4.z); o.w = f2bf(x.w * scale * w4.w);
    *(ushort4*)(xn + (size_t)m * HID + (t << 2)) = o;
}

// ---------------- MFMA GEMM 1 + fused gates ----------------
// 256 rows x (4 gates x 64 s-cols), BK=64, 8 waves, round-9 schedule (frozen).
// B-tile LDS row r: gate g = r>>6, s = s0 + (r&63); global col = g*4096 + s.
// Epilogue: xg,a_l,b_l,c_l in-register -> writes a=sig(a_l), bx=sig(b_l)*xg,
// c=sig(c_l) as bf16 [4096][4096] each (96 MiB total vs 128 MiB raw proj).
__global__ __launch_bounds__(512, 2) void gemm_in_mfma(
    const unsigned short* __restrict__ A, const unsigned short* __restrict__ B,
    const float* __restrict__ bias,
    unsigned short* __restrict__ a_out, unsigned short* __restrict__ bx_out,
    unsigned short* __restrict__ c_out)
{
    extern __shared__ unsigned short lds[];   // 2 bufs * 32768 shorts = 128 KiB
    int tid = threadIdx.x;
    int wid = tid >> 6, lane = tid & 63;
    int wg = blockIdx.x;
    int xcd = wg & 7, loc = wg >> 3;
    int by = ((xcd >> 1) << 2) + (loc & 3);   // 0..15  m-tile
    int bx = ((xcd & 1) << 5) + (loc >> 2);   // 0..63  s-slab
    int m0 = by * 256, s0 = bx * 64;
    int wm = wid >> 2, wn = wid & 3;
    int lr = lane & 15, lk = lane >> 4;

    int cb0 = wid * 64, cb1 = 512 + wid * 64;
    int p0 = cb0 + lane, p1 = cb1 + lane;
    int row0 = p0 >> 2, ks0 = (p0 & 3) ^ ((row0 >> 1) & 3);
    int row1 = p1 >> 2, ks1 = (p1 & 3) ^ ((row1 >> 1) & 3);
    // A global rows
    int arow0 = m0 + row0, arow1 = m0 + row1;
    // B global rows: gate-major tile row -> column (r>>6)*4096 + s0 + (r&63)
    int brow0 = ((row0 >> 6) << 12) + s0 + (row0 & 63);
    int brow1 = ((row1 >> 6) << 12) + s0 + (row1 & 63);

#define SHALF(grow0, grow1, b, which, kt, kk) do {                               \
    unsigned short* _d = lds + (b) * 32768 + (which) * 16384 + (kk) * 8192;      \
    __builtin_amdgcn_global_load_lds(                                            \
        (gptr_t)(const void*)(((which) ? B : A) + (size_t)(grow0) * 1024 +       \
                              (kt) * 64 + (kk) * 32 + ks0 * 8),                  \
        (lptr_t)(void*)(_d + (size_t)cb0 * 8), 16, 0, 0);                        \
    __builtin_amdgcn_global_load_lds(                                            \
        (gptr_t)(const void*)(((which) ? B : A) + (size_t)(grow1) * 1024 +       \
                              (kt) * 64 + (kk) * 32 + ks1 * 8),                  \
        (lptr_t)(void*)(_d + (size_t)cb1 * 8), 16, 0, 0);                        \
} while (0)

    int ksw = lk ^ ((lr >> 1) & 3);

#define RD_A(b, kk, mf) \
    (*(const short8v*)&lds[(b) * 32768 + (kk) * 8192 + \
        (((wm * 128 + (mf) * 16 + lr) << 2) + ksw) * 8])
    // B-frag nf = gate index; tile row = nf*64 + wn*16 + lr
#define RD_B(b, kk, nf) \
    (*(const short8v*)&lds[(b) * 32768 + 16384 + (kk) * 8192 + \
        ((((nf) * 64 + wn * 16 + lr) << 2) + ksw) * 8])

#define MFMA8x2(AF, B0, B1, n0i, n1i) do {                                       \
    __builtin_amdgcn_s_setprio(1);                                               \
    _Pragma("unroll")                                                            \
    for (int mf = 0; mf < 8; mf++) {                                             \
        acc[mf][n0i] = __builtin_amdgcn_mfma_f32_16x16x32_bf16(                  \
            (AF)[mf], (B0), acc[mf][n0i], 0, 0, 0);                              \
        acc[mf][n1i] = __builtin_amdgcn_mfma_f32_16x16x32_bf16(                  \
            (AF)[mf], (B1), acc[mf][n1i], 0, 0, 0);                              \
    }                                                                            \
    __builtin_amdgcn_s_setprio(0);                                               \
} while (0)

#define BAR_IN()  do { __builtin_amdgcn_s_barrier();                              \
    asm volatile("s_waitcnt lgkmcnt(0)" ::: "memory");                           \
    __builtin_amdgcn_sched_barrier(0); } while (0)
#define BAR_OUT() do { asm volatile("" ::: "memory");                             \
    __builtin_amdgcn_s_barrier(); } while (0)

    float4v acc[8][4];
    float4v z = {0.f, 0.f, 0.f, 0.f};
    #pragma unroll
    for (int i = 0; i < 8; i++)
        #pragma unroll
        for (int j = 0; j < 4; j++) acc[i][j] = z;

    SHALF(arow0, arow1, 0, 0, 0, 0); SHALF(brow0, brow1, 0, 1, 0, 0);
    SHALF(arow0, arow1, 0, 0, 0, 1); SHALF(brow0, brow1, 0, 1, 0, 1);
    asm volatile("s_waitcnt vmcnt(0)" ::: "memory");
    __builtin_amdgcn_s_barrier();

    short8v af[8], bf0, bf1;

    for (int kt = 0; kt < 16; ++kt) {
        int cur = kt & 1, nxt = cur ^ 1;
        int ktn = kt < 15 ? kt + 1 : 15;
        // phase 0: kk0, gates 0-1
        #pragma unroll
        for (int mf = 0; mf < 8; mf++) af[mf] = RD_A(cur, 0, mf);
        bf0 = RD_B(cur, 0, 0); bf1 = RD_B(cur, 0, 1);
        asm volatile("s_waitcnt vmcnt(4)" ::: "memory");
        SHALF(arow0, arow1, nxt, 0, ktn, 0);
        BAR_IN();
        MFMA8x2(af, bf0, bf1, 0, 1);
        BAR_OUT();
        // phase 1: kk0, gates 2-3
        bf0 = RD_B(cur, 0, 2); bf1 = RD_B(cur, 0, 3);
        SHALF(brow0, brow1, nxt, 1, ktn, 0);
        BAR_IN();
        MFMA8x2(af, bf0, bf1, 2, 3);
        BAR_OUT();
        // phase 2: kk1, gates 0-1
        #pragma unroll
        for (int mf = 0; mf < 8; mf++) af[mf] = RD_A(cur, 1, mf);
        bf0 = RD_B(cur, 1, 0); bf1 = RD_B(cur, 1, 1);
        asm volatile("s_waitcnt vmcnt(4)" ::: "memory");
        SHALF(arow0, arow1, nxt, 0, ktn, 1);
        BAR_IN();
        MFMA8x2(af, bf0, bf1, 0, 1);
        BAR_OUT();
        // phase 3: kk1, gates 2-3
        bf0 = RD_B(cur, 1, 2); bf1 = RD_B(cur, 1, 3);
        SHALF(brow0, brow1, nxt, 1, ktn, 1);
        BAR_IN();
        MFMA8x2(af, bf0, bf1, 2, 3);
        BAR_OUT();
    }

    // fused-gate epilogue
    int s = s0 + wn * 16 + lr;
    float b_xg = bias[s];
    float b_a  = bias[4096 + s];
    float b_b  = bias[8192 + s];
    float b_c  = bias[12288 + s];
    int rbase = lk << 2;
    #pragma unroll
    for (int mf = 0; mf < 8; mf++)
        #pragma unroll
        for (int q = 0; q < 4; q++) {
            int m = m0 + wm * 128 + mf * 16 + rbase + q;
            size_t idx = (size_t)m * STT + s;
            float xg = acc[mf][0][q] + b_xg;
            float a  = sigmoidf_(acc[mf][1][q] + b_a);
            float bxv = sigmoidf_(acc[mf][2][q] + b_b) * xg;
            float c  = sigmoidf_(acc[mf][3][q] + b_c);
            a_out[idx]  = f2bf(a);
            bx_out[idx] = f2bf(bxv);
            c_out[idx]  = f2bf(c);
        }
#undef SHALF
#undef RD_A
#undef RD_B
#undef MFMA8x2
#undef BAR_IN
#undef BAR_OUT
}

// ---------------- MFMA GEMM 2: out = y @ out_w + out_b + residual (f32 out) --
// 128x128 tile, BK=32, 4 waves (2x2), 3-buffer depth-2 pipeline, chunk swizzle.
__global__ __launch_bounds__(256, 3) void gemm_out_mfma(
    const unsigned short* __restrict__ A, const unsigned short* __restrict__ B,
    const float* __restrict__ out_b, const int* __restrict__ tokens,
    const float* __restrict__ embed_w, float* __restrict__ Cout)
{
    extern __shared__ unsigned short lds[];   // 3 bufs * (4096 A + 4096 B) = 48 KiB
    int tid = threadIdx.x;
    int wid = tid >> 6, lane = tid & 63;
    int wg = blockIdx.x;                      // 256 WGs: 8 n-tiles x 32 m-tiles
    int swz = (wg & 7) * 32 + (wg >> 3);
    int bx = swz & 7;
    int by = swz >> 3;
    int m0 = by * 128, n0 = bx * 128;
    int wm = wid >> 1, wn = wid & 1;
    int lr = lane & 15, lk = lane >> 4;

    auto stage = [&](int b, int kt) {
        unsigned short* As = lds + b * 8192;
        unsigned short* Bs = As + 4096;
        #pragma unroll
        for (int i = 0; i < 2; i++) {
            int cb = i * 256 + wid * 64;
            int p = cb + lane;
            int row = p >> 2;
            int ks = (p & 3) ^ ((row >> 1) & 3);
            __builtin_amdgcn_global_load_lds(
                (gptr_t)(const void*)(A + (size_t)(m0 + row) * 4096 + kt + ks * 8),
                (lptr_t)(void*)(As + (size_t)cb * 8), 16, 0, 0);
            __builtin_amdgcn_global_load_lds(
                (gptr_t)(const void*)(B + (size_t)(n0 + row) * 4096 + kt + ks * 8),
                (lptr_t)(void*)(Bs + (size_t)cb * 8), 16, 0, 0);
        }
    };

    float4v acc[4][4];
    float4v z = {0.f, 0.f, 0.f, 0.f};
    #pragma unroll
    for (int i = 0; i < 4; i++)
        #pragma unroll
        for (int j = 0; j < 4; j++) acc[i][j] = z;

    const int nt = 4096 / 32;
    stage(0, 0); stage(1, 32);

    int ksw = lk ^ ((lr >> 1) & 3);
    int aoff = lr * 4 + ksw;

    for (int t = 0; t < nt; ++t) {
        if (t + 2 < nt) stage((t + 2) % 3, (t + 2) * 32);
        if (t + 2 < nt)      asm volatile("s_waitcnt vmcnt(8)" ::: "memory");
        else if (t + 1 < nt) asm volatile("s_waitcnt vmcnt(4)" ::: "memory");
        else                 asm volatile("s_waitcnt vmcnt(0)" ::: "memory");
        __builtin_amdgcn_s_barrier();
        asm volatile("" ::: "memory");
        const unsigned short* As = lds + (t % 3) * 8192;
        const unsigned short* Bs = As + 4096;
        short8v af[4], bfr[4];
        #pragma unroll
        for (int f = 0; f < 4; f++) {
            af[f]  = *(const short8v*)&As[((wm * 64 + f * 16) * 4 + aoff) * 8];
            bfr[f] = *(const short8v*)&Bs[((wn * 64 + f * 16) * 4 + aoff) * 8];
        }
        __builtin_amdgcn_s_setprio(1);
        #pragma unroll
        for (int mf = 0; mf < 4; mf++)
            #pragma unroll
            for (int nf = 0; nf < 4; nf++)
                acc[mf][nf] = __builtin_amdgcn_mfma_f32_16x16x32_bf16(
                    af[mf], bfr[nf], acc[mf][nf], 0, 0, 0);
        __builtin_amdgcn_s_setprio(0);
        asm volatile("" ::: "memory");
        __builtin_amdgcn_s_barrier();
    }

    int rbase = lk << 2;
    #pragma unroll
    for (int mf = 0; mf < 4; mf++) {
        #pragma unroll
        for (int q = 0; q < 4; q++) {
            int m = m0 + wm * 64 + mf * 16 + rbase + q;
            int tok = tokens[m];
            #pragma unroll
            for (int nf = 0; nf < 4; nf++) {
                int n = n0 + wn * 64 + nf * 16 + lr;
                float v = acc[mf][nf][q] + out_b[n] + embed_w[(size_t)tok * HID + n];
                Cout[(size_t)m * HID + n] = v;
            }
        }
    }
}

// ---------------- scan phase 1: per-chunk (A, H) from fused gates ----------
// grid 512 = 4 sg x 64 q x 2 b; 4 ch/thread, ushort4 loads
__global__ __launch_bounds__(256) void scan_phase1(
    const unsigned short* __restrict__ a_buf, const unsigned short* __restrict__ bx_buf,
    float* __restrict__ chunkA, float* __restrict__ chunkH)
{
    int bid = blockIdx.x;
    int sg = bid & 3, q = (bid >> 2) & 63, b = bid >> 8;
    int s0 = sg * 1024 + threadIdx.x * 4;
    size_t base = (size_t)(b * LSEQ + q * CHUNK) * STT + s0;
    const unsigned short* ap = a_buf + base;
    const unsigned short* bp = bx_buf + base;
    float Aa[4] = {1.f, 1.f, 1.f, 1.f}, Hh[4] = {0.f, 0.f, 0.f, 0.f};
    for (int t = 0; t < CHUNK; t++) {
        ushort4 Av = *(const ushort4*)ap;
        ushort4 Bv = *(const ushort4*)bp;
        const unsigned short* avp = (const unsigned short*)&Av;
        const unsigned short* bvp = (const unsigned short*)&Bv;
        #pragma unroll
        for (int j = 0; j < 4; j++) {
            float a = bf2f(avp[j]);
            Hh[j] = fmaf(a, Hh[j], bf2f(bvp[j]));
            Aa[j] *= a;
        }
        ap += STT; bp += STT;
    }
    #pragma unroll
    for (int j = 0; j < 4; j++) {
        int ch = b * STT + s0 + j;
        chunkA[ch * NCHUNK + q] = Aa[j];
        chunkH[ch * NCHUNK + q] = Hh[j];
    }
}

__global__ __launch_bounds__(256) void scan_phase2(
    const float* __restrict__ chunkA, const float* __restrict__ chunkH,
    float* __restrict__ carry)
{
    int ch = blockIdx.x * 256 + threadIdx.x;
    float c = 0.f;
    for (int q = 0; q < NCHUNK; q++) {
        carry[ch * NCHUNK + q] = c;
        c = fmaf(chunkA[ch * NCHUNK + q], c, chunkH[ch * NCHUNK + q]);
    }
}

// ---------------- scan phase 3: y = c * h, 4 ch/thread ----------
__global__ __launch_bounds__(256) void scan_phase3(
    const unsigned short* __restrict__ a_buf, const unsigned short* __restrict__ bx_buf,
    const unsigned short* __restrict__ c_buf, const float* __restrict__ carry,
    unsigned short* __restrict__ y)
{
    int bid = blockIdx.x;
    int sg = bid & 3, q = (bid >> 2) & 63, b = bid >> 8;
    int s0 = sg * 1024 + threadIdx.x * 4;
    float h[4];
    #pragma unroll
    for (int j = 0; j < 4; j++)
        h[j] = carry[(b * STT + s0 + j) * NCHUNK + q];
    size_t base = (size_t)(b * LSEQ + q * CHUNK) * STT + s0;
    const unsigned short* ap = a_buf + base;
    const unsigned short* bp = bx_buf + base;
    const unsigned short* cp = c_buf + base;
    unsigned short* yp = y + base;
    for (int t = 0; t < CHUNK; t++) {
        ushort4 Av = *(const ushort4*)ap;
        ushort4 Bv = *(const ushort4*)bp;
        ushort4 Cv = *(const ushort4*)cp;
        const unsigned short* avp = (const unsigned short*)&Av;
        const unsigned short* bvp = (const unsigned short*)&Bv;
        const unsigned short* cvp = (const unsigned short*)&Cv;
        ushort4 o;
        unsigned short* op = (unsigned short*)&o;
        #pragma unroll
        for (int j = 0; j < 4; j++) {
            h[j] = fmaf(bf2f(avp[j]), h[j], bf2f(bvp[j]));
            op[j] = f2bf(bf2f(cvp[j]) * h[j]);
        }
        *(ushort4*)yp = o;
        ap += STT; bp += STT; cp += STT; yp += STT;
    }
}

// ---------------- head GEMM: 256 threads/token, 4-way k-split ----------------
__global__ __launch_bounds__(256) void head_kernel(
    const float* __restrict__ out, const float* __restrict__ head_w,
    const float* __restrict__ head_b, float* __restrict__ logits)
{
    __shared__ float row[HID];
    __shared__ float part[4][64];
    int m = blockIdx.x;
    int t = threadIdx.x;
    ((float4*)row)[t] = ((const float4*)(out + (size_t)m * HID))[t];
    __syncthreads();
    int v = t & 63, ks = t >> 6;
    float s = 0.f;
    if (v < VOCAB) {
        const float* wcol = head_w + (size_t)(ks * 256) * VOCAB + v;
        const float* rb = row + ks * 256;
        #pragma unroll 4
        for (int k = 0; k < 256; k++)
            s = fmaf(rb[k], wcol[(size_t)k * VOCAB], s);
    }
    part[ks][v] = s;
    __syncthreads();
    if (t < VOCAB)
        logits[(size_t)m * VOCAB + t] =
            part[0][t] + part[1][t] + part[2][t] + part[3][t] + head_b[t];
}

extern "C" void kernel_launch(void* const* d_in, const int* in_sizes, int n_in,
                              void* d_out, int out_size, void* d_ws, size_t ws_size,
                              hipStream_t stream) {
    const int*   tokens  = (const int*)d_in[0];
    const float* embed_w = (const float*)d_in[1];
    const float* norm_w  = (const float*)d_in[2];
    const float* in_w    = (const float*)d_in[3];
    const float* in_b    = (const float*)d_in[4];
    const float* out_w   = (const float*)d_in[5];
    const float* out_b   = (const float*)d_in[6];
    const float* head_w  = (const float*)d_in[7];
    const float* head_b  = (const float*)d_in[8];
    float* logits = (float*)d_out;

    char* w = (char*)d_ws;
    unsigned short* a_buf  = (unsigned short*)w;                    // 32 MiB
    unsigned short* bx_buf = (unsigned short*)(w + 33554432);       // 32 MiB
    unsigned short* c_buf  = (unsigned short*)(w + 67108864);       // 32 MiB
    unsigned short* y      = (unsigned short*)(w + 134217728);      // 32 MiB
    unsigned short* in_wT  = (unsigned short*)(w + 167772160);      // 32 MiB
    float*          outbuf = (float*)(w + 167772160);               // reuses in_wT
    unsigned short* xn     = (unsigned short*)(w + 201326592);      // 8 MiB
    unsigned short* out_wT = (unsigned short*)(w + 201326592);      // reuses xn
    float* chunkA = (float*)(w + 209715200);
    float* chunkH = chunkA + 8192 * NCHUNK;
    float* carry  = chunkH + 8192 * NCHUNK;

    hipLaunchKernelGGL(cast_transpose_kernel, dim3(16384 / 32, 1024 / 32), dim3(256), 0, stream,
                       in_w, in_wT, 1024, 16384);
    hipLaunchKernelGGL(embed_norm_kernel, dim3(MTOK), dim3(256), 0, stream,
                       tokens, embed_w, norm_w, xn);
    hipLaunchKernelGGL(gemm_in_mfma, dim3(1024), dim3(512), 131072, stream,
                       xn, in_wT, in_b, a_buf, bx_buf, c_buf);
    hipLaunchKernelGGL(scan_phase1, dim3(512), dim3(256), 0, stream,
                       a_buf, bx_buf, chunkA, chunkH);
    hipLaunchKernelGGL(scan_phase2, dim3(32), dim3(256), 0, stream,
                       chunkA, chunkH, carry);
    hipLaunchKernelGGL(scan_phase3, dim3(512), dim3(256), 0, stream,
                       a_buf, bx_buf, c_buf, carry, y);
    hipLaunchKernelGGL(cast_transpose_kernel, dim3(1024 / 32, 4096 / 32), dim3(256), 0, stream,
                       out_w, out_wT, 4096, 1024);
    hipLaunchKernelGGL(gemm_out_mfma, dim3(256), dim3(256), 49152, stream,
                       y, out_wT, out_b, tokens, embed_w, outbuf);
    hipLaunchKernelGGL(head_kernel, dim3(MTOK), dim3(256), 0, stream,
                       outbuf, head_w, head_b, logits);
}